// Round 1
// baseline (663.567 us; speedup 1.0000x reference)
//
#include <hip/hip_runtime.h>

// GroupLinearBlock: out = einsum('nhd,hdf', (rmsnorm_h(x@W) + b)/sqrt2, K)
// Fused single-pass design:
//   prep: wt[N][K] = bf16(w_lin[K][N]);  kt[h][f][d] = bf16(kernel[h][d][f])
//   main: per block: 32 token rows x all 16 heads.
//     stage x(f32->bf16) -> LDS (padded stride 1032), GEMM1 via 16x16x32 MFMA
//     (B-frags direct from L2-resident wt), per-head RMSNorm via shfl_xor
//     butterfly, bias blend, LDS re-layout (C-frag -> A-frag), GEMM2 via MFMA,
//     f32 stores.

typedef __attribute__((ext_vector_type(8))) __bf16 bf16x8;
typedef __attribute__((ext_vector_type(4))) float f32x4;
typedef __attribute__((ext_vector_type(4))) unsigned int uint4v;

__device__ __forceinline__ unsigned short f2bf(float f) {
  unsigned int u = __builtin_bit_cast(unsigned int, f);
  u += 0x7FFFu + ((u >> 16) & 1u);      // round-to-nearest-even
  return (unsigned short)(u >> 16);
}

__device__ __forceinline__ f32x4 mfma_bf16(bf16x8 a, bf16x8 b, f32x4 c) {
  return __builtin_amdgcn_mfma_f32_16x16x32_bf16(a, b, c, 0, 0, 0);
}

// ---- prep: w_lin [K=1024][N=1024] f32 -> wt [N][K] bf16 ----
__global__ void transpose_w(const float* __restrict__ w, unsigned short* __restrict__ wt) {
  __shared__ float tile[32][33];
  const int n0 = blockIdx.x * 32, k0 = blockIdx.y * 32;
  const int tx = threadIdx.x, ty = threadIdx.y;   // 32 x 8
  #pragma unroll
  for (int j = 0; j < 32; j += 8)
    tile[ty + j][tx] = w[(size_t)(k0 + ty + j) * 1024 + n0 + tx];
  __syncthreads();
  #pragma unroll
  for (int j = 0; j < 32; j += 8)
    wt[(size_t)(n0 + ty + j) * 1024 + k0 + tx] = f2bf(tile[tx][ty + j]);
}

// ---- prep: kernel [16][d=64][f=64] f32 -> kt [16][f][d] bf16 ----
__global__ void transpose_k(const float* __restrict__ kin, unsigned short* __restrict__ kt) {
  __shared__ float tile[64][65];
  const int h = blockIdx.x;
  const int t = threadIdx.x;                       // 256
  #pragma unroll
  for (int i = 0; i < 16; ++i) {
    int idx = i * 256 + t;                         // d = idx>>6, f = idx&63
    tile[idx >> 6][idx & 63] = kin[(size_t)h * 4096 + idx];
  }
  __syncthreads();
  #pragma unroll
  for (int i = 0; i < 16; ++i) {
    int idx = i * 256 + t;                         // f = idx>>6, d = idx&63
    kt[(size_t)h * 4096 + idx] = f2bf(tile[idx & 63][idx >> 6]);
  }
}

// ---- main fused kernel: grid 65536/32 = 2048 blocks, 512 threads (8 waves) ----
__global__ __launch_bounds__(512, 2)
void fused_main(const float* __restrict__ x,
                const float* __restrict__ nbias,
                const unsigned short* __restrict__ wt,
                const unsigned short* __restrict__ kt,
                float* __restrict__ out)
{
  // x tile: 32 rows x 1024 bf16, row stride 1032 (+16B pad -> only 2-way bank
  // aliasing on the stride-row A-fragment ds_read_b128, which is free).
  __shared__ __align__(16) unsigned short smem[32 * 1032];   // 66048 B
  const int tid  = threadIdx.x;
  const int wv   = tid >> 6;          // wave 0..7: owns cols [128*wv, 128*wv+128)
  const int lane = tid & 63;
  const int l15  = lane & 15;
  const int lg   = lane >> 4;         // 0..3
  const size_t row0 = (size_t)blockIdx.x * 32;

  { // stage x (f32 -> bf16) into LDS; fully coalesced 32B/thread/iter
    const float* xs = x + row0 * 1024;
    #pragma unroll
    for (int it = 0; it < 8; ++it) {
      const int g = (it * 512 + tid) * 8;          // flat elem idx in 32x1024 tile
      const int r = g >> 10, c = g & 1023;
      f32x4 a = *reinterpret_cast<const f32x4*>(xs + g);
      f32x4 b = *reinterpret_cast<const f32x4*>(xs + g + 4);
      uint4v p;
      p[0] = (unsigned)f2bf(a[0]) | ((unsigned)f2bf(a[1]) << 16);
      p[1] = (unsigned)f2bf(a[2]) | ((unsigned)f2bf(a[3]) << 16);
      p[2] = (unsigned)f2bf(b[0]) | ((unsigned)f2bf(b[1]) << 16);
      p[3] = (unsigned)f2bf(b[2]) | ((unsigned)f2bf(b[3]) << 16);
      *reinterpret_cast<uint4v*>(&smem[r * 1032 + c]) = p;
    }
  }
  __syncthreads();

  // ---- GEMM1: acc[mf][nf] = x_tile @ W[:, wave cols] ----
  const f32x4 z4 = {0.f, 0.f, 0.f, 0.f};
  f32x4 acc[2][8];
  #pragma unroll
  for (int mf = 0; mf < 2; ++mf)
    #pragma unroll
    for (int nf = 0; nf < 8; ++nf) acc[mf][nf] = z4;

  // B-frag: lane holds wt[col=wv*128+16*nf+l15][k0 + 8*lg .. +8] (16B contig)
  const unsigned short* wtb = wt + (size_t)(wv * 128 + l15) * 1024 + 8 * lg;
  // A-frag: lane holds x_lds[row=l15(+16)][k0 + 8*lg .. +8]
  const unsigned short* a0p = &smem[l15 * 1032 + 8 * lg];

  #pragma unroll 2
  for (int k0 = 0; k0 < 1024; k0 += 32) {
    bf16x8 a0 = *reinterpret_cast<const bf16x8*>(a0p + k0);
    bf16x8 a1 = *reinterpret_cast<const bf16x8*>(a0p + 16 * 1032 + k0);
    #pragma unroll
    for (int nf = 0; nf < 8; ++nf) {
      bf16x8 b = *reinterpret_cast<const bf16x8*>(wtb + nf * 16384 + k0);
      acc[0][nf] = mfma_bf16(a0, b, acc[0][nf]);
      acc[1][nf] = mfma_bf16(a1, b, acc[1][nf]);
    }
  }

  __syncthreads();   // all waves done reading x tile; reuse smem for y

  unsigned short* ylds = &smem[wv * 2304];   // per-wave 32 rows x 72 bf16 (pad 8)

  #pragma unroll
  for (int hl = 0; hl < 2; ++hl) {
    const int h = 2 * wv + hl;

    // ---- RMSNorm + bias blend; write y bf16 to per-wave LDS [row][d] ----
    #pragma unroll
    for (int mf = 0; mf < 2; ++mf) {
      float ss[4];
      #pragma unroll
      for (int r = 0; r < 4; ++r) {
        float p = 0.f;
        #pragma unroll
        for (int nf = 0; nf < 4; ++nf) { const float v = acc[mf][hl*4+nf][r]; p += v * v; }
        ss[r] = p;
      }
      #pragma unroll
      for (int s = 1; s < 16; s <<= 1)
        #pragma unroll
        for (int r = 0; r < 4; ++r) ss[r] += __shfl_xor(ss[r], s, 64);
      #pragma unroll
      for (int r = 0; r < 4; ++r) {
        const float rs = rsqrtf(ss[r] * 0.015625f + 1e-6f);   // mean over 64 + eps
        const int rl = mf * 16 + lg * 4 + r;                  // local row 0..31
        const float* bp = nbias + (row0 + rl) * 1024 + h * 64 + l15;
        #pragma unroll
        for (int nf = 0; nf < 4; ++nf) {
          const float y = (acc[mf][hl*4+nf][r] * rs + bp[nf * 16]) * 0.70710678118654752f;
          ylds[rl * 72 + nf * 16 + l15] = f2bf(y);
        }
      }
    }

    // ---- GEMM2: out_head = y[32][64] @ kernel[h][64][64] ----
    f32x4 acc2[2][4];
    #pragma unroll
    for (int m2 = 0; m2 < 2; ++m2)
      #pragma unroll
      for (int ff = 0; ff < 4; ++ff) acc2[m2][ff] = z4;

    const unsigned short* ktb = kt + (size_t)h * 4096 + (size_t)l15 * 64 + 8 * lg;
    #pragma unroll
    for (int ks = 0; ks < 2; ++ks) {
      bf16x8 a0 = *reinterpret_cast<const bf16x8*>(&ylds[l15 * 72 + ks * 32 + 8 * lg]);
      bf16x8 a1 = *reinterpret_cast<const bf16x8*>(&ylds[(16 + l15) * 72 + ks * 32 + 8 * lg]);
      #pragma unroll
      for (int ff = 0; ff < 4; ++ff) {
        bf16x8 b = *reinterpret_cast<const bf16x8*>(ktb + ff * 1024 + ks * 32);
        acc2[0][ff] = mfma_bf16(a0, b, acc2[0][ff]);
        acc2[1][ff] = mfma_bf16(a1, b, acc2[1][ff]);
      }
    }

    #pragma unroll
    for (int m2 = 0; m2 < 2; ++m2)
      #pragma unroll
      for (int ff = 0; ff < 4; ++ff)
        #pragma unroll
        for (int r = 0; r < 4; ++r)
          out[(row0 + m2 * 16 + lg * 4 + r) * 1024 + h * 64 + ff * 16 + l15] = acc2[m2][ff][r];
  }
}

extern "C" void kernel_launch(void* const* d_in, const int* in_sizes, int n_in,
                              void* d_out, int out_size, void* d_ws, size_t ws_size,
                              hipStream_t stream) {
  const float* x  = (const float*)d_in[0];   // [65536][1024]
  const float* nb = (const float*)d_in[1];   // [65536][16][64]
  const float* wl = (const float*)d_in[2];   // [1024][1024]
  const float* kr = (const float*)d_in[3];   // [16][64][64]
  float* out = (float*)d_out;                // [65536][1024] f32

  unsigned short* wt = (unsigned short*)d_ws;            // 2 MB
  unsigned short* kt = wt + 1024 * 1024;                 // 128 KB

  hipLaunchKernelGGL(transpose_w, dim3(32, 32), dim3(32, 8), 0, stream, wl, wt);
  hipLaunchKernelGGL(transpose_k, dim3(16), dim3(256), 0, stream, kr, kt);
  hipLaunchKernelGGL(fused_main, dim3(65536 / 32), dim3(512), 0, stream, x, nb, wt, kt, out);
}

// Round 2
// 291.739 us; speedup vs baseline: 2.2745x; 2.2745x over previous
//
#include <hip/hip_runtime.h>

// GroupLinearBlock: out = einsum('nhd,hdf', (rmsnorm_h(x@W) + b)/sqrt2, K)
// m97-structure 128x128-tile GEMM1 (global_load_lds staging, dbuf, XOR-swizzled
// f32 A tile, pre-blocked bf16 B), fused per-wave RMSNorm+bias+GEMM2 epilogue.

typedef __attribute__((ext_vector_type(8))) __bf16 bf16x8;
typedef __attribute__((ext_vector_type(4))) float f32x4;
typedef __attribute__((ext_vector_type(8))) unsigned short ushort8;

__device__ __forceinline__ unsigned short f2bf(float f) {
  unsigned int u = __builtin_bit_cast(unsigned int, f);
  u += 0x7FFFu + ((u >> 16) & 1u);
  return (unsigned short)(u >> 16);
}

__device__ __forceinline__ f32x4 mfma_bf16(bf16x8 a, bf16x8 b, f32x4 c) {
  return __builtin_amdgcn_mfma_f32_16x16x32_bf16(a, b, c, 0, 0, 0);
}

__device__ __forceinline__ void gl_lds16(const void* g, void* l) {
  __builtin_amdgcn_global_load_lds(
      (const __attribute__((address_space(1))) unsigned int*)g,
      (__attribute__((address_space(3))) unsigned int*)l, 16, 0, 0);
}

// ---- prep: w_lin [k=1024][n=1024] f32 -> wb[ct(8)][kg(128)][col(128)][8] bf16
// (exact LDS staging order: flat-copy staging, conflict-free frag reads)
__global__ void prep_w(const float* __restrict__ w, unsigned short* __restrict__ wb) {
  const int kg = blockIdx.x, ct = blockIdx.y, col = threadIdx.x;   // 128 thr
  const int n = ct * 128 + col;
  ushort8 v;
  #pragma unroll
  for (int j = 0; j < 8; ++j) v[j] = f2bf(w[(size_t)(kg * 8 + j) * 1024 + n]);
  *reinterpret_cast<ushort8*>(wb + ((size_t)(ct * 128 + kg) * 128 + col) * 8) = v;
}

// ---- prep: kernel [16][d=64][f=64] f32 -> kt [16][f][d] bf16 ----
__global__ void transpose_k(const float* __restrict__ kin, unsigned short* __restrict__ kt) {
  __shared__ float tile[64][65];
  const int h = blockIdx.x;
  const int t = threadIdx.x;                       // 256
  #pragma unroll
  for (int i = 0; i < 16; ++i) {
    int idx = i * 256 + t;
    tile[idx >> 6][idx & 63] = kin[(size_t)h * 4096 + idx];
  }
  __syncthreads();
  #pragma unroll
  for (int i = 0; i < 16; ++i) {
    int idx = i * 256 + t;
    kt[(size_t)h * 4096 + idx] = f2bf(tile[idx & 63][idx >> 6]);
  }
}

// ---- main: 4096 blocks x 256 threads; tile 128 rows x 128 cols, K=1024 ----
__global__ __launch_bounds__(256, 3)
void fused_main(const float* __restrict__ x,
                const float* __restrict__ nbias,
                const unsigned short* __restrict__ wb,
                const unsigned short* __restrict__ kt,
                float* __restrict__ out)
{
  // LDS: A dbuf 2x16KB (f32, XOR-swizzled rows of 128B) + B dbuf 2x8KB
  // ([kc(4)][col(128)][16B], flat copy of wb). Epilogue reuses as y (64x80 bf16/wave).
  __shared__ __align__(16) unsigned char smem[49152];
  const int tid  = threadIdx.x;
  const int wv   = tid >> 6, lane = tid & 63;
  const int l15  = lane & 15, lg = lane >> 4;
  const int wr   = wv >> 1, wc = wv & 1;       // wave tile: rows wr*64, cols wc*64

  // XCD swizzle: xcd g = bid&7 handles row-tiles rt ≡ g (mod 8); consecutive
  // slots sweep the 8 col-tiles of one rt -> A-panel (512KB) reused from L2.
  const int bid  = blockIdx.x;
  const int gx   = bid & 7, slot = bid >> 3;
  const int rt   = ((slot >> 3) << 3) + gx;    // 0..511
  const int ct   = slot & 7;                   // 0..7
  const size_t row0 = (size_t)rt * 128;

  const float* xb = x + row0 * 1024;
  const unsigned short* wbase = wb + (size_t)ct * 131072;

  f32x4 acc[4][4];
  const f32x4 z4 = {0.f, 0.f, 0.f, 0.f};
  #pragma unroll
  for (int mi = 0; mi < 4; ++mi)
    #pragma unroll
    for (int ni = 0; ni < 4; ++ni) acc[mi][ni] = z4;

  // ---- staging helpers (dest linear, src pre-permuted per rule 21) ----
  auto stageA = [&](int t, unsigned char* Ab) {
    #pragma unroll
    for (int it = 0; it < 4; ++it) {
      const int L = it * 4096 + tid * 16;                 // byte in 16KB tile
      const int row = L >> 7;
      const int off = (L & 127) ^ ((row & 7) << 4);       // inverse swizzle
      gl_lds16(xb + (size_t)row * 1024 + t * 32 + (off >> 2), Ab + L);
    }
  };
  auto stageB = [&](int t, unsigned char* Bb) {
    #pragma unroll
    for (int it = 0; it < 2; ++it) {
      const int L = it * 4096 + tid * 16;                 // byte in 8KB tile
      gl_lds16(wbase + t * 4096 + (L >> 1), Bb + L);      // flat copy
    }
  };

  stageA(0, smem);
  stageB(0, smem + 32768);

  for (int t = 0; t < 32; ++t) {
    __syncthreads();                      // vmcnt(0) drain: buf[t&1] ready
    const int nb = (t + 1) & 1;
    if (t < 31) {
      stageA(t + 1, smem + (nb << 14));
      stageB(t + 1, smem + 32768 + (nb << 13));
    }
    const unsigned char* A = smem + ((t & 1) << 14);
    const unsigned char* B = smem + 32768 + ((t & 1) << 13);

    bf16x8 af[4], bfr[4];
    #pragma unroll
    for (int mi = 0; mi < 4; ++mi) {
      const int row = wr * 64 + mi * 16 + l15;
      const int base = row * 128 + ((lg * 32) ^ ((row & 7) << 4));
      f32x4 lo = *reinterpret_cast<const f32x4*>(A + base);
      f32x4 hi = *reinterpret_cast<const f32x4*>(A + (base ^ 16));
      bf16x8 a;
      #pragma unroll
      for (int j = 0; j < 4; ++j) { a[j] = (__bf16)lo[j]; a[4 + j] = (__bf16)hi[j]; }
      af[mi] = a;
    }
    #pragma unroll
    for (int ni = 0; ni < 4; ++ni) {
      const int col = wc * 64 + ni * 16 + l15;
      bfr[ni] = *reinterpret_cast<const bf16x8*>(B + lg * 2048 + col * 16);
    }
    #pragma unroll
    for (int mi = 0; mi < 4; ++mi)
      #pragma unroll
      for (int ni = 0; ni < 4; ++ni)
        acc[mi][ni] = mfma_bf16(af[mi], bfr[ni], acc[mi][ni]);
  }

  __syncthreads();    // all waves done with A/B LDS; reuse for y

  // ---- epilogue: per-head RMSNorm + bias blend -> y (bf16, LDS) -> GEMM2 ----
  const int h = ct * 2 + wc;                         // wave's head
  unsigned short* yw = reinterpret_cast<unsigned short*>(smem) + wv * 5120; // 64x80
  const float* bb = nbias + (row0 + wr * 64) * 1024 + (size_t)h * 64 + l15;

  #pragma unroll
  for (int mi = 0; mi < 4; ++mi) {
    float ss[4];
    #pragma unroll
    for (int r = 0; r < 4; ++r) {
      float p = 0.f;
      #pragma unroll
      for (int ni = 0; ni < 4; ++ni) { const float v = acc[mi][ni][r]; p += v * v; }
      ss[r] = p;
    }
    #pragma unroll
    for (int s = 1; s < 16; s <<= 1)
      #pragma unroll
      for (int r = 0; r < 4; ++r) ss[r] += __shfl_xor(ss[r], s, 64);
    #pragma unroll
    for (int r = 0; r < 4; ++r) {
      const float rs = rsqrtf(ss[r] * 0.015625f + 1e-6f);
      const int rl = mi * 16 + lg * 4 + r;           // row within wave
      const float* bp = bb + (size_t)rl * 1024;
      #pragma unroll
      for (int ni = 0; ni < 4; ++ni) {
        const float y = (acc[mi][ni][r] * rs + bp[ni * 16]) * 0.70710678118654752f;
        __bf16 yb = (__bf16)y;
        yw[rl * 80 + ni * 16 + l15] = __builtin_bit_cast(unsigned short, yb);
      }
    }
  }

  // GEMM2: y[64][64] @ kt[h][f][d]  (A from LDS stride-80, B frags from L2)
  const unsigned short* ktp = kt + (size_t)h * 4096;
  bf16x8 b2[4][2];
  #pragma unroll
  for (int ff = 0; ff < 4; ++ff)
    #pragma unroll
    for (int ks = 0; ks < 2; ++ks)
      b2[ff][ks] = *reinterpret_cast<const bf16x8*>(ktp + (ff * 16 + l15) * 64 + ks * 32 + 8 * lg);

  #pragma unroll
  for (int m2 = 0; m2 < 4; ++m2) {
    f32x4 a2[4] = {z4, z4, z4, z4};
    #pragma unroll
    for (int ks = 0; ks < 2; ++ks) {
      bf16x8 a = *reinterpret_cast<const bf16x8*>(yw + (m2 * 16 + l15) * 80 + ks * 32 + 8 * lg);
      #pragma unroll
      for (int ff = 0; ff < 4; ++ff) a2[ff] = mfma_bf16(a, b2[ff][ks], a2[ff]);
    }
    float* ob = out + (row0 + wr * 64 + m2 * 16 + lg * 4) * 1024 + ct * 128 + wc * 64 + l15;
    #pragma unroll
    for (int ff = 0; ff < 4; ++ff)
      #pragma unroll
      for (int r = 0; r < 4; ++r)
        ob[(size_t)r * 1024 + ff * 16] = a2[ff][r];
  }
}

extern "C" void kernel_launch(void* const* d_in, const int* in_sizes, int n_in,
                              void* d_out, int out_size, void* d_ws, size_t ws_size,
                              hipStream_t stream) {
  const float* x  = (const float*)d_in[0];   // [65536][1024]
  const float* nb = (const float*)d_in[1];   // [65536][16][64]
  const float* wl = (const float*)d_in[2];   // [1024][1024]
  const float* kr = (const float*)d_in[3];   // [16][64][64]
  float* out = (float*)d_out;

  unsigned short* wbp = (unsigned short*)d_ws;           // 2 MB blocked W
  unsigned short* ktp = wbp + 1024 * 1024;               // 128 KB

  hipLaunchKernelGGL(prep_w, dim3(128, 8), dim3(128), 0, stream, wl, wbp);
  hipLaunchKernelGGL(transpose_k, dim3(16), dim3(256), 0, stream, kr, ktp);
  hipLaunchKernelGGL(fused_main, dim3(4096), dim3(256), 0, stream, x, nb, wbp, ktp, out);
}